// Round 8
// baseline (180.463 us; speedup 1.0000x reference)
//
#include <hip/hip_runtime.h>
#include <float.h>

// Problem constants (fixed by reference: B=8, D=64, H=64, W=64, K=8192)
constexpr int KCODES = 8192;
constexpr int DDIM   = 64;
constexpr int NTOK   = 32768;
constexpr int MT     = 64;                 // tokens per WG (4 sets x 16)
constexpr int KC     = 64;                 // codes per chunk
constexpr int NCH    = KCODES / KC;        // 128 chunks
constexpr int CBCHUNK = KC * DDIM * 2 * 2; // 16384 B (64 codes x 64 d x bf16 x {hi,lo})

typedef short v8s __attribute__((ext_vector_type(8)));
typedef float v4f __attribute__((ext_vector_type(4)));

static __device__ __forceinline__ unsigned short f2bf(float f) {
  union { float f; unsigned u; } v; v.f = f;
  return (unsigned short)((v.u + 0x7fffu + ((v.u >> 16) & 1u)) >> 16);  // RNE
}
static __device__ __forceinline__ float bf2f(unsigned short b) {
  union { unsigned u; float f; } v; v.u = (unsigned)b << 16;
  return v.f;
}

// ---- fused prep: bf16 hi/lo split, FRAGMENT-LINEAR for mfma_16x16x32_bf16
// A-operand (A[m=lane&15][k=(lane>>4)*8+j]), + biased half-norms
// hn[k] = 0.5*||c_k||^2 + 2.0 (bias keeps phase-1 scores positive -> fp32
// bit pattern monotone for the packed-key argmin).
// Per chunk c: byte off = c*16384 + term*2048 + ks*1024 + lane*16 + j*2, per g block of 4096.
__global__ __launch_bounds__(256) void prep_kernel(
    const float* __restrict__ cb, unsigned short* __restrict__ wcb,
    float* __restrict__ hn) {
  const int c = blockIdx.x;                 // chunk 0..127
  const int tid = threadIdx.x;
  const int g = tid >> 6, lane = tid & 63;
  const int quad = lane >> 4, col = lane & 15;
  const int code = c * KC + g * 16 + col;
  const float* src = cb + (size_t)code * DDIM;
  float sq = 0.f;
#pragma unroll
  for (int ks = 0; ks < 2; ++ks) {
    v8s hi, lo;
#pragma unroll
    for (int j = 0; j < 8; ++j) {
      const float x = src[ks * 32 + quad * 8 + j];
      sq += x * x;
      const unsigned short h = f2bf(x);
      const unsigned short l = f2bf(x - bf2f(h));   // residual (Sterbenz-exact sub)
      hi[j] = (short)h; lo[j] = (short)l;
    }
    const size_t b0 = ((size_t)c * CBCHUNK + g * 4096 + ks * 1024 + lane * 16) / 2;
    *reinterpret_cast<v8s*>(wcb + b0)        = hi;
    *reinterpret_cast<v8s*>(wcb + b0 + 1024) = lo;
  }
  sq += __shfl_xor(sq, 16);
  sq += __shfl_xor(sq, 32);
  if (quad == 0) hn[code] = 0.5f * sq + 2.0f;
}

// Phase 1: bf16-split MFMA, A-frags register-double-buffered straight from
//   global (fully coalesced dwordx4; per-wave private stream -> NO k-loop
//   barriers, no hot-loop LDS; compiler schedules waits via SSA deps).
// Phase 2: fast path when the approx argmin is unambiguous (single candidate
//   within smin+1e-4); numpy-fp32-faithful refine only for near-ties
//   (pairwise-8 sums, D=fl(fl(S-2p)+N), correctly-rounded-fp64 p,
//   tie -> lowest index) - semantics identical to the passing rounds.
__global__ __launch_bounds__(256, 2) void vq_kernel(
    const float* __restrict__ ze, const float* __restrict__ cb,
    const float* __restrict__ hn, const unsigned short* __restrict__ wcb,
    float* __restrict__ out) {
  __shared__ float c_s1[16 * MT];   // per-cell best score  [cell][token]
  __shared__ float c_s2[16 * MT];   // per-cell 2nd best
  __shared__ int   c_i1[16 * MT];
  __shared__ int   c_i2[16 * MT];
  __shared__ int   widx[MT];

  const int tid = threadIdx.x, lane = tid & 63, wv = tid >> 6;
  const int col = lane & 15, quad = lane >> 4;
  const int t0 = blockIdx.x * MT;
  const int bb = t0 >> 12, hw0 = t0 & 4095;   // 4096 % 64 == 0: one batch per WG
  const float* zb = ze + (size_t)bb * (DDIM * 4096) + hw0;

  // ---- B-frags: 4 sets x 16 tokens, negated + bf16-split, in registers.
  // B[k=(lane>>4)*8+j][n=lane&15]; token = s*16 + col; d = ks*32 + quad*8 + j.
  v8s nxh[4][2], nxl[4][2];
#pragma unroll
  for (int s = 0; s < 4; ++s) {
    const int mtok = s * 16 + col;
#pragma unroll
    for (int ks = 0; ks < 2; ++ks) {
#pragma unroll
      for (int j = 0; j < 8; ++j) {
        const int d = ks * 32 + quad * 8 + j;
        const float x = -zb[(size_t)d * 4096 + mtok];
        const unsigned short h = f2bf(x);
        const unsigned short l = f2bf(x - bf2f(h));
        nxh[s][ks][j] = (short)h; nxl[s][ks][j] = (short)l;
      }
    }
  }

  // ---- A-frag register double buffer; each lane's 4 x 16B loads are the
  // wave's 4 x 1KB coalesced term-blocks {hi-ks0, hi-ks1, lo-ks0, lo-ks1}.
  const char* abase = (const char*)wcb + wv * 4096 + lane * 16;
  const float* hnp  = hn + wv * 16 + quad * 4;

  auto loadA = [&](v8s (&A)[4], v4f& hv, int it) {
    const char* p = abase + (size_t)it * CBCHUNK;
    A[0] = *reinterpret_cast<const v8s*>(p);
    A[1] = *reinterpret_cast<const v8s*>(p + 1024);
    A[2] = *reinterpret_cast<const v8s*>(p + 2048);
    A[3] = *reinterpret_cast<const v8s*>(p + 3072);
    hv = *reinterpret_cast<const v4f*>(hnp + (size_t)it * KC);
  };

  float bs1[4], bs2[4];
  int   bi1[4], bi2[4];
#pragma unroll
  for (int s = 0; s < 4; ++s) { bs1[s] = bs2[s] = FLT_MAX; bi1[s] = bi2[s] = 0; }

  const int kb0 = wv * 16 + quad * 4;

  auto compute = [&](const v8s (&A)[4], const v4f hv, int it) {
    v4f acc[4];
#pragma unroll
    for (int s = 0; s < 4; ++s) acc[s] = hv;
#pragma unroll
    for (int s = 0; s < 4; ++s)
      acc[s] = __builtin_amdgcn_mfma_f32_16x16x32_bf16(A[0], nxh[s][0], acc[s], 0, 0, 0);
#pragma unroll
    for (int s = 0; s < 4; ++s)
      acc[s] = __builtin_amdgcn_mfma_f32_16x16x32_bf16(A[1], nxh[s][1], acc[s], 0, 0, 0);
#pragma unroll
    for (int s = 0; s < 4; ++s)
      acc[s] = __builtin_amdgcn_mfma_f32_16x16x32_bf16(A[2], nxh[s][0], acc[s], 0, 0, 0);
#pragma unroll
    for (int s = 0; s < 4; ++s)
      acc[s] = __builtin_amdgcn_mfma_f32_16x16x32_bf16(A[3], nxh[s][1], acc[s], 0, 0, 0);
#pragma unroll
    for (int s = 0; s < 4; ++s)
      acc[s] = __builtin_amdgcn_mfma_f32_16x16x32_bf16(A[0], nxl[s][0], acc[s], 0, 0, 0);
#pragma unroll
    for (int s = 0; s < 4; ++s)
      acc[s] = __builtin_amdgcn_mfma_f32_16x16x32_bf16(A[1], nxl[s][1], acc[s], 0, 0, 0);

    const int kbase = it * KC + kb0;
#pragma unroll
    for (int s = 0; s < 4; ++s) {
      unsigned km = 0xFFFFFFFFu;   // packed (score-bits & ~3) | local-idx
#pragma unroll
      for (int r = 0; r < 4; ++r)
        km = min(km, (__float_as_uint(acc[s][r]) & ~3u) | (unsigned)r);
      const float sc = __uint_as_float(km & ~3u);   // biased (+2.0) approx score
      const int k = kbase + (int)(km & 3u);
      if (sc < bs1[s])      { bs2[s] = bs1[s]; bi2[s] = bi1[s]; bs1[s] = sc; bi1[s] = k; }
      else if (sc < bs2[s]) { bs2[s] = sc; bi2[s] = k; }
    }
  };

  v8s A0[4], A1[4]; v4f h0, h1;
  loadA(A0, h0, 0); loadA(A1, h1, 1);

  for (int it = 0; it < NCH; it += 2) {
    compute(A0, h0, it);
    if (it + 2 < NCH) loadA(A0, h0, it + 2);
    compute(A1, h1, it + 1);
    if (it + 3 < NCH) loadA(A1, h1, it + 3);
  }

  // ---- surface per-cell top-2 (cell = wv*4+quad; 16 cells x 512 codes) ----
  {
    const int cell = wv * 4 + quad;
#pragma unroll
    for (int s = 0; s < 4; ++s) {
      const int m = s * 16 + col;
      c_s1[cell * MT + m] = bs1[s];  c_i1[cell * MT + m] = bi1[s];
      c_s2[cell * MT + m] = bs2[s];  c_i2[cell * MT + m] = bi2[s];
    }
  }
  __syncthreads();

  // ---- phase 2: fast path or numpy-faithful refine ----
  if (tid < MT) {
#pragma clang fp contract(off)   // numpy: separate mul then add; no FMA
    const int m = tid;

    float smin = FLT_MAX; int fidx = 0x7fffffff;
    for (int c = 0; c < 16; ++c) {
      const float a = c_s1[c * MT + m];
      if (a < smin) { smin = a; fidx = c_i1[c * MT + m]; }
    }
    const float lim = smin + 1e-4f;   // covers approx err ~1.4e-5 + trunc 1e-6
                                      // + numpy ulp(64) quantization ~1.5e-5
    int cnt = 0;
    for (int c = 0; c < 16; ++c) {
      cnt += (c_s1[c * MT + m] <= lim);
      cnt += (c_s2[c * MT + m] <= lim);
    }

    int besti;
    if (cnt == 1) {
      // unique candidate within margin: approx argmin == numpy argmin
      besti = fidx;
    } else {
      // near-tie: numpy-fp32-faithful decision over all in-margin candidates
      const float* xz = zb + m;
      float xm[DDIM];
      for (int d = 0; d < DDIM; ++d) xm[d] = xz[(size_t)d * 4096];

      float r[8];
      for (int j = 0; j < 8; ++j) r[j] = xm[j] * xm[j];
      for (int i = 8; i < DDIM; i += 8)
        for (int j = 0; j < 8; ++j) r[j] += xm[i + j] * xm[i + j];
      const float S = ((r[0] + r[1]) + (r[2] + r[3])) + ((r[4] + r[5]) + (r[6] + r[7]));

      float bestD = FLT_MAX;
      besti = 0x7fffffff;
      for (int c = 0; c < 16; ++c) {
        for (int h = 0; h < 2; ++h) {
          const float sp = h ? c_s2[c * MT + m] : c_s1[c * MT + m];
          if (sp > lim) continue;
          const int idx = h ? c_i2[c * MT + m] : c_i1[c * MT + m];
          const float* crow = cb + (size_t)idx * DDIM;

          float rn[8];
          for (int j = 0; j < 8; ++j) rn[j] = crow[j] * crow[j];
          for (int i = 8; i < DDIM; i += 8)
            for (int j = 0; j < 8; ++j) rn[j] += crow[i + j] * crow[i + j];
          const float Nk =
              ((rn[0] + rn[1]) + (rn[2] + rn[3])) + ((rn[4] + rn[5]) + (rn[6] + rn[7]));

          double p64 = 0.0;
          for (int d = 0; d < DDIM; ++d) p64 += (double)xm[d] * (double)crow[d];
          const float pf = (float)p64;

          const float twop = 2.0f * pf;
          const float t1   = S - twop;
          const float Dv   = t1 + Nk;
          if (Dv < bestD || (Dv == bestD && idx < besti)) { bestD = Dv; besti = idx; }
        }
      }
    }
    widx[m] = besti;
  }
  __syncthreads();

  // ---- gather winners, write z_q (coalesced 64-float rows; cb L2-hot) ----
  {
    const int wi = widx[lane];
    const float* crow = cb + (size_t)wi * DDIM;
    float* ob = out + (size_t)bb * (DDIM * 4096) + hw0;
#pragma unroll
    for (int p = 0; p < 16; ++p) {
      const int d = wv * 16 + p;
      ob[(size_t)d * 4096 + lane] = crow[d];
    }
  }
}

extern "C" void kernel_launch(void* const* d_in, const int* in_sizes, int n_in,
                              void* d_out, int out_size, void* d_ws, size_t ws_size,
                              hipStream_t stream) {
  const float* ze = (const float*)d_in[0];    // [8,64,64,64]
  const float* cb = (const float*)d_in[1];    // [8192,64]
  float* hn = (float*)d_ws;                                     // 32 KB
  unsigned short* wcb = (unsigned short*)((char*)d_ws + 32768); // 2 MB frag-linear split
  float* out = (float*)d_out;

  prep_kernel<<<NCH, 256, 0, stream>>>(cb, wcb, hn);
  vq_kernel<<<NTOK / MT, 256, 0, stream>>>(ze, cb, hn, wcb, out);
}